// Round 9
// baseline (70.745 us; speedup 1.0000x reference)
//
#include <hip/hip_runtime.h>
#include <hip/hip_cooperative_groups.h>

namespace cg = cooperative_groups;

typedef __attribute__((ext_vector_type(4))) float f32x4;

constexpr int Bdim = 8192;   // rows of x
constexpr int Cdim = 4096;   // rows of W (= output cols)
constexpr int Ddim = 256;    // K
constexpr int NBLK = 512;    // cooperative grid: 2 blocks/CU on 256 CUs

// 15*exp(-t) == +0.0f in f32 (incl. denormal range) for t >= ~106.7; margin -> 112.
constexpr float ZERO_THRESH = 112.0f;

// ---------------------------------------------------------------------------
// Single cooperative kernel.
// Phase 1 (per block, one HBM ramp): partial max of ||W||^2 over its 8 W rows
//   -> pm[bid]; stage its 16 x rows in LDS + per-row norms (doubles as the
//   slow path's staging).
// grid.sync()
// Phase 2: per-wave scan of pm[512] -> global max||W|| (block-uniform, no
//   barrier); then 4 slabs of 4 rows, each screened via Cauchy-Schwarz:
//   ||x_b - w_c||^2 >= (||x_b|| - max||W||)^2 > 112  =>  every slab output is
//   exactly 15*exp(-metric) == +0.0f in f32 -> linear f32x4 zero fill
//   (regular stores: L2 write-combine is the fast path; NT stores -25%, R5).
//   Slow path (block-uniform; not taken for the bench input): exact f32.
// ---------------------------------------------------------------------------
__global__ __launch_bounds__(256) void rbf_fused(const float* __restrict__ x,
                                                 const float* __restrict__ W,
                                                 float* __restrict__ pm,
                                                 float* __restrict__ out) {
  __shared__ float xl[16][Ddim];   // 16 KB staged x rows
  __shared__ float norms[16];      // per-row ||x||^2
  __shared__ float sm[4];          // per-wave W partial max

  int tid  = threadIdx.x;
  int lane = tid & 63;
  int wid  = tid >> 6;
  int bid  = blockIdx.x;
  int row_base = bid * 16;

  // ---- phase 1a: partial max ||W||^2 over this block's 8 W rows ----
  float pmax = 0.0f;
  #pragma unroll
  for (int r = 0; r < 2; ++r) {
    int row = bid * 8 + wid * 2 + r;
    f32x4 v = *(const f32x4*)(W + (size_t)row * Ddim + lane * 4);
    float s = v[0]*v[0] + v[1]*v[1] + v[2]*v[2] + v[3]*v[3];
    #pragma unroll
    for (int off = 32; off > 0; off >>= 1) s += __shfl_xor(s, off, 64);
    pmax = fmaxf(pmax, s);
  }
  if (lane == 0) sm[wid] = pmax;

  // ---- phase 1b: stage 16 x rows -> LDS + per-row norms ----
  #pragma unroll
  for (int i = 0; i < 4; ++i) {
    int idx = i * 256 + tid;                 // f32x4 index; 64 per row
    f32x4 v = *(const f32x4*)(x + (size_t)row_base * Ddim + (size_t)idx * 4);
    *(f32x4*)&xl[i * 4 + wid][lane * 4] = v;
    float s = v[0]*v[0] + v[1]*v[1] + v[2]*v[2] + v[3]*v[3];
    #pragma unroll
    for (int off = 32; off > 0; off >>= 1) s += __shfl_xor(s, off, 64);
    if (lane == 0) norms[i * 4 + wid] = s;
  }
  __syncthreads();
  if (tid == 0) pm[bid] = fmaxf(fmaxf(sm[0], sm[1]), fmaxf(sm[2], sm[3]));

  cg::this_grid().sync();

  // ---- phase 2: global max ||W||^2 (per-wave scan, block-uniform) ----
  const f32x4* p4 = (const f32x4*)pm;        // 128 f32x4 = 512 f32
  f32x4 q0 = p4[lane];
  f32x4 q1 = p4[lane + 64];
  float wmx = fmaxf(fmaxf(fmaxf(q0[0], q0[1]), fmaxf(q0[2], q0[3])),
                    fmaxf(fmaxf(q1[0], q1[1]), fmaxf(q1[2], q1[3])));
  #pragma unroll
  for (int off = 32; off > 0; off >>= 1) wmx = fmaxf(wmx, __shfl_xor(wmx, off, 64));
  float wnorm = sqrtf(wmx);

  // ---- 4 slabs of 4 rows each ----
  #pragma unroll 1
  for (int s = 0; s < 4; ++s) {
    int row0 = row_base + s * 4;
    float xmin = fminf(fminf(norms[s*4+0], norms[s*4+1]),
                       fminf(norms[s*4+2], norms[s*4+3]));
    float gap = sqrtf(xmin) - wnorm;

    if (gap > 0.0f && gap * gap > ZERO_THRESH) {
      // fast path: 64 KB contiguous zero fill, regular f32x4 stores
      f32x4 z = {0.0f, 0.0f, 0.0f, 0.0f};
      float* base = out + (size_t)row0 * Cdim + tid * 4;
      #pragma unroll
      for (int p = 0; p < 16; ++p)
        *(f32x4*)(base + (size_t)p * 1024) = z;
    } else {
      // slow path: exact f32 metric (xl staged in phase 1b; block-uniform)
      for (int ch = 0; ch < Cdim / 256; ++ch) {
        int col = ch * 256 + tid;
        const float* wrow = W + (size_t)col * Ddim;
        float m0 = 0.f, m1 = 0.f, m2 = 0.f, m3 = 0.f;
        for (int d = 0; d < Ddim; d += 4) {
          f32x4 wv = *(const f32x4*)(wrow + d);
          #pragma unroll
          for (int e = 0; e < 4; ++e) {
            float w  = wv[e];
            float d0 = w - xl[s*4+0][d + e]; m0 += d0 * d0;
            float d1 = w - xl[s*4+1][d + e]; m1 += d1 * d1;
            float d2 = w - xl[s*4+2][d + e]; m2 += d2 * d2;
            float d3 = w - xl[s*4+3][d + e]; m3 += d3 * d3;
          }
        }
        out[(size_t)(row0 + 0) * Cdim + col] = 15.0f * expf(-m0);
        out[(size_t)(row0 + 1) * Cdim + col] = 15.0f * expf(-m1);
        out[(size_t)(row0 + 2) * Cdim + col] = 15.0f * expf(-m2);
        out[(size_t)(row0 + 3) * Cdim + col] = 15.0f * expf(-m3);
      }
    }
  }
}

extern "C" void kernel_launch(void* const* d_in, const int* in_sizes, int n_in,
                              void* d_out, int out_size, void* d_ws, size_t ws_size,
                              hipStream_t stream) {
  const float* x = (const float*)d_in[0];   // [8192, 256] f32
  const float* W = (const float*)d_in[1];   // [4096, 256] f32
  float* out     = (float*)d_out;           // [8192, 4096] f32
  float* pm      = (float*)d_ws;            // 512 f32 = 2 KB scratch

  void* args[] = { (void*)&x, (void*)&W, (void*)&pm, (void*)&out };
  hipLaunchCooperativeKernel((const void*)rbf_fused, dim3(NBLK), dim3(256),
                             args, 0, stream);
}

// Round 10
// 27.977 us; speedup vs baseline: 2.5287x; 2.5287x over previous
//
#include <hip/hip_runtime.h>

typedef __attribute__((ext_vector_type(4))) float f32x4;

constexpr int Bdim = 8192;   // rows of x
constexpr int Cdim = 4096;   // rows of W (= output cols)
constexpr int Ddim = 256;    // K

// 15*exp(-t) == +0.0f in f32 (incl. denormal range) for t >= ~106.7; margin -> 112.
constexpr float ZERO_THRESH = 112.0f;

// ---------------------------------------------------------------------------
// Kernel 1: norms pass.
//   blocks 0..2047   : xmin[b]  = min ||x_row||^2 over the slab's 4 rows
//   blocks 2048..3071: pmax[b'] = max ||W_row||^2 over 4 W rows
// Reads 12.6 MB, writes 12 KB. (sum-reduce per row, then min/max across waves)
// ---------------------------------------------------------------------------
__global__ __launch_bounds__(256) void norms_kernel(const float* __restrict__ x,
                                                    const float* __restrict__ W,
                                                    float* __restrict__ xmin,
                                                    float* __restrict__ pmax) {
  __shared__ float sm[4];
  int tid  = threadIdx.x;
  int lane = tid & 63;
  int wid  = tid >> 6;
  int b    = blockIdx.x;

  if (b < Bdim / 4) {
    int row = b * 4 + wid;
    f32x4 v = *(const f32x4*)(x + (size_t)row * Ddim + lane * 4);
    float s = v[0]*v[0] + v[1]*v[1] + v[2]*v[2] + v[3]*v[3];
    #pragma unroll
    for (int off = 32; off > 0; off >>= 1) s += __shfl_xor(s, off, 64);
    if (lane == 0) sm[wid] = s;
    __syncthreads();
    if (tid == 0) xmin[b] = fminf(fminf(sm[0], sm[1]), fminf(sm[2], sm[3]));
  } else {
    int row = (b - Bdim / 4) * 4 + wid;
    f32x4 v = *(const f32x4*)(W + (size_t)row * Ddim + lane * 4);
    float s = v[0]*v[0] + v[1]*v[1] + v[2]*v[2] + v[3]*v[3];
    #pragma unroll
    for (int off = 32; off > 0; off >>= 1) s += __shfl_xor(s, off, 64);
    if (lane == 0) sm[wid] = s;
    __syncthreads();
    if (tid == 0) pmax[b - Bdim / 4] = fmaxf(fmaxf(sm[0], sm[1]), fmaxf(sm[2], sm[3]));
  }
}

// ---------------------------------------------------------------------------
// Kernel 2: 2048 blocks x one 4-row slab (64 KB contiguous).
// UNCONDITIONAL zero fill first — the 16 f32x4 stores have no input
// dependencies, so the store stream starts at cycle 0 (fill-kernel profile).
// The Cauchy-Schwarz screen (||x_b - w_c||^2 >= (||x_b|| - max||W||)^2 > 112
// => slab outputs are exactly 15*exp(-metric) == +0.0f in f32) is evaluated
// CONCURRENTLY from L2-hot precomputed norms. Screen pass (bench input:
// always) -> return, zeros are the exact output. Screen fail (block-uniform)
// -> __syncthreads() drains the zero stores (vmcnt 0 before s_barrier; same
// CU => same XCD L2, coherent), then exact f32 compute overwrites the slab.
// Regular stores (NT stores measured -25% in R5).
// ---------------------------------------------------------------------------
__global__ __launch_bounds__(256) void rbf_fill(const float* __restrict__ x,
                                                const float* __restrict__ W,
                                                const float* __restrict__ xmin,
                                                const float* __restrict__ pmax,
                                                float* __restrict__ out) {
  __shared__ float xl[4][Ddim];   // slow path only (4 KB)

  int tid  = threadIdx.x;
  int lane = tid & 63;
  int wid  = tid >> 6;
  int slab = blockIdx.x;
  int row0 = slab * 4;

  // ---- unconditional fast fill: 64 KB contiguous, zero dependencies ----
  f32x4 z = {0.0f, 0.0f, 0.0f, 0.0f};
  float* base = out + (size_t)row0 * Cdim + tid * 4;
  #pragma unroll
  for (int p = 0; p < 16; ++p)
    *(f32x4*)(base + (size_t)p * 1024) = z;

  // ---- screen, concurrent with the store stream (L2-hot loads) ----
  float xm = xmin[slab];
  const f32x4* pm4 = (const f32x4*)pmax;      // 256 f32x4 = 1024 f32
  f32x4 q0 = pm4[lane];
  f32x4 q1 = pm4[lane + 64];
  f32x4 q2 = pm4[lane + 128];
  f32x4 q3 = pm4[lane + 192];
  float wmx = fmaxf(fmaxf(fmaxf(q0[0], q0[1]), fmaxf(q0[2], q0[3])),
                    fmaxf(fmaxf(q1[0], q1[1]), fmaxf(q1[2], q1[3])));
  wmx = fmaxf(wmx, fmaxf(fmaxf(fmaxf(q2[0], q2[1]), fmaxf(q2[2], q2[3])),
                         fmaxf(fmaxf(q3[0], q3[1]), fmaxf(q3[2], q3[3]))));
  #pragma unroll
  for (int off = 32; off > 0; off >>= 1) wmx = fmaxf(wmx, __shfl_xor(wmx, off, 64));

  float gap = sqrtf(xm) - sqrtf(wmx);
  if (gap > 0.0f && gap * gap > ZERO_THRESH) return;   // zeros are exact

  // ---- slow path (block-uniform; not taken for the bench input) ----
  __syncthreads();   // drain zero-fill stores before cross-thread overwrite
  {
    f32x4 v = *(const f32x4*)(x + (size_t)row0 * Ddim + tid * 4);
    *(f32x4*)&xl[wid][lane * 4] = v;
  }
  __syncthreads();
  for (int ch = 0; ch < Cdim / 256; ++ch) {
    int col = ch * 256 + tid;
    const float* wrow = W + (size_t)col * Ddim;
    float m0 = 0.f, m1 = 0.f, m2 = 0.f, m3 = 0.f;
    for (int d = 0; d < Ddim; d += 4) {
      f32x4 wv = *(const f32x4*)(wrow + d);
      #pragma unroll
      for (int e = 0; e < 4; ++e) {
        float w  = wv[e];
        float d0 = w - xl[0][d + e]; m0 += d0 * d0;
        float d1 = w - xl[1][d + e]; m1 += d1 * d1;
        float d2 = w - xl[2][d + e]; m2 += d2 * d2;
        float d3 = w - xl[3][d + e]; m3 += d3 * d3;
      }
    }
    out[(size_t)(row0 + 0) * Cdim + col] = 15.0f * expf(-m0);
    out[(size_t)(row0 + 1) * Cdim + col] = 15.0f * expf(-m1);
    out[(size_t)(row0 + 2) * Cdim + col] = 15.0f * expf(-m2);
    out[(size_t)(row0 + 3) * Cdim + col] = 15.0f * expf(-m3);
  }
}

extern "C" void kernel_launch(void* const* d_in, const int* in_sizes, int n_in,
                              void* d_out, int out_size, void* d_ws, size_t ws_size,
                              hipStream_t stream) {
  const float* x = (const float*)d_in[0];   // [8192, 256] f32
  const float* W = (const float*)d_in[1];   // [4096, 256] f32
  float* out     = (float*)d_out;           // [8192, 4096] f32
  float* xmin    = (float*)d_ws;            // 2048 f32
  float* pmax    = xmin + Bdim / 4;         // 1024 f32 (12 KB total)

  // 1) per-slab x-norm mins + W-norm partial maxes (12.6 MB read)
  norms_kernel<<<Bdim / 4 + Cdim / 4, 256, 0, stream>>>(x, W, xmin, pmax);

  // 2) unconditional-fill + concurrent screen: 2048 blocks x 4 rows
  rbf_fill<<<Bdim / 4, 256, 0, stream>>>(x, W, xmin, pmax, out);
}